// Round 2
// baseline (183.216 us; speedup 1.0000x reference)
//
#include <hip/hip_runtime.h>

// ParamMakeFeature: out[b,:,n] = D_b * mlp(R_b^T x[b,:,n])
// Folded form: A1 = W1*R^T (layer-1 absorbs un-rotation),
//              A3 = D*W3, c3 = D*b3 (layer-3 absorbs re-rotation),
// where D = blockdiag(Q1 R Q1^T, Q2 (RxR) Q2^T, Q3 (RxRxR) Q3^T).
// Single kernel: each block derives the per-batch folded params in LDS
// (cheap: ~10 kFLOP), then streams 512 points through the 3->15->15->15 MLP.
//
// B=32, N=65536, FEAT_SUM=15 (blocks 3,5,7).

#define PSTRIDE 544  // [0..59] A1 15x{w0,w1,w2,b1} | [64..303] W2' 15x16 | [304..543] A3' 15x16

__global__ __launch_bounds__(256, 4) void fused_all(
    const float* __restrict__ x, const float* __restrict__ Rg,
    const float* __restrict__ W1, const float* __restrict__ b1,
    const float* __restrict__ W2, const float* __restrict__ b2,
    const float* __restrict__ W3, const float* __restrict__ b3,
    const float* __restrict__ Q1, const float* __restrict__ Q2,
    const float* __restrict__ Q3,
    float* __restrict__ out, int N) {
  __shared__ float sR[9], sQ1[9], sQ2s[45], sQ3s[189];
  __shared__ float sW3r[225], sb3[15];
  __shared__ float sK2[81], sK3[729];
  __shared__ float sT2[45], sT3[189];
  __shared__ float sD1[9], sD2[25], sD3[49];
  __shared__ float sP[PSTRIDE];

  const int b = blockIdx.y;
  const int t = threadIdx.x;

  // ---- prefetch this thread's x (independent of prep; hides HBM latency) ----
  const int n0 = (blockIdx.x * 256 + t) * 2;
  float2 xa = make_float2(0.f, 0.f), xm = xa, xc = xa;
  if (n0 < N) {
    const float* xb = x + (size_t)b * 3 * N + n0;
    xa = *(const float2*)(xb);
    xm = *(const float2*)(xb + N);
    xc = *(const float2*)(xb + 2 * N);
  }

  // ---- phase 0: stage small tensors into LDS ----
  if (t < 9) sR[t] = Rg[b * 9 + t];
  else if (t >= 16 && t < 25) sQ1[t - 16] = Q1[t - 16];
  else if (t >= 32 && t < 47) sb3[t - 32] = b3[t - 32];
  for (int i = t; i < 45; i += 256) sQ2s[i] = Q2[i];
  for (int i = t; i < 189; i += 256) sQ3s[i] = Q3[i];
  for (int i = t; i < 225; i += 256) sW3r[i] = W3[i];
  __syncthreads();

  // ---- phase 1: Kronecker powers ----
  for (int i = t; i < 81; i += 256) {
    int r = i / 9, c = i % 9;
    sK2[i] = sR[(r / 3) * 3 + (c / 3)] * sR[(r % 3) * 3 + (c % 3)];
  }
  for (int i = t; i < 729; i += 256) {
    int r = i / 27, c = i % 27;
    sK3[i] = sR[(r / 9) * 3 + (c / 9)] *
             sR[((r / 3) % 3) * 3 + ((c / 3) % 3)] *
             sR[(r % 3) * 3 + (c % 3)];
  }
  __syncthreads();

  // ---- phase 2: T_l = K_l * Q_l^T ----
  for (int i = t; i < 45; i += 256) {
    int r = i / 5, q = i % 5;
    float acc = 0.f;
    for (int c = 0; c < 9; ++c) acc += sK2[r * 9 + c] * sQ2s[q * 9 + c];
    sT2[i] = acc;
  }
  for (int i = t; i < 189; i += 256) {
    int r = i / 7, q = i % 7;
    float acc = 0.f;
    for (int c = 0; c < 27; ++c) acc += sK3[r * 27 + c] * sQ3s[q * 27 + c];
    sT3[i] = acc;
  }
  __syncthreads();

  // ---- phase 3: D_l = Q_l * T_l ----
  if (t < 9) {
    int p = t / 3, q = t % 3;
    float acc = 0.f;
    for (int ii = 0; ii < 3; ++ii)
      for (int jj = 0; jj < 3; ++jj)
        acc += sQ1[p * 3 + ii] * sR[ii * 3 + jj] * sQ1[q * 3 + jj];
    sD1[t] = acc;
  } else if (t >= 32 && t < 57) {
    int i = t - 32, p = i / 5, q = i % 5;
    float acc = 0.f;
    for (int r = 0; r < 9; ++r) acc += sQ2s[p * 9 + r] * sT2[r * 5 + q];
    sD2[i] = acc;
  } else if (t >= 64 && t < 113) {
    int i = t - 64, p = i / 7, q = i % 7;
    float acc = 0.f;
    for (int r = 0; r < 27; ++r) acc += sQ3s[p * 27 + r] * sT3[r * 7 + q];
    sD3[i] = acc;
  }
  __syncthreads();

  // ---- phase 4: folded params into sP ----
  if (t < 15) {  // A1 rows: A1[f][j] = sum_i W1[f,i]*R[j,i]; [3]=b1[f]
    int f = t;
    for (int j = 0; j < 3; ++j) {
      float acc = 0.f;
      for (int i2 = 0; i2 < 3; ++i2) acc += W1[f * 3 + i2] * sR[j * 3 + i2];
      sP[f * 4 + j] = acc;
    }
    sP[f * 4 + 3] = b1[f];
  }
  for (int i = t; i < 240; i += 256) {  // W2 rows + b2
    int f = i / 16, k = i % 16;
    sP[64 + i] = (k < 15) ? W2[f * 15 + k] : b2[f];
  }
  for (int i = t; i < 240; i += 256) {  // A3 = D*W3 rows + c3 = D*b3
    int f = i / 16, k = i % 16;
    float acc = 0.f;
    if (f < 3) {
      for (int q = 0; q < 3; ++q)
        acc += sD1[f * 3 + q] * ((k < 15) ? sW3r[q * 15 + k] : sb3[q]);
    } else if (f < 8) {
      for (int q = 0; q < 5; ++q)
        acc += sD2[(f - 3) * 5 + q] * ((k < 15) ? sW3r[(q + 3) * 15 + k] : sb3[q + 3]);
    } else {
      for (int q = 0; q < 7; ++q)
        acc += sD3[(f - 8) * 7 + q] * ((k < 15) ? sW3r[(q + 8) * 15 + k] : sb3[q + 8]);
    }
    sP[304 + i] = acc;
  }
  __syncthreads();

  // ---- main: 2 points/thread through the folded MLP ----
  if (n0 >= N) return;

  float h1[15][2];
#pragma unroll
  for (int f = 0; f < 15; ++f) {
    float4 w = ((const float4*)sP)[f];
    h1[f][0] = fmaxf(fmaf(w.x, xa.x, fmaf(w.y, xm.x, fmaf(w.z, xc.x, w.w))), 0.f);
    h1[f][1] = fmaxf(fmaf(w.x, xa.y, fmaf(w.y, xm.y, fmaf(w.z, xc.y, w.w))), 0.f);
  }

  float h2[15][2];
#pragma unroll
  for (int f = 0; f < 15; ++f) {
    const float* row = sP + 64 + f * 16;
    float bias = row[15];
    float a0 = bias, a1 = bias;
#pragma unroll
    for (int g = 0; g < 15; ++g) {
      float w = row[g];
      a0 = fmaf(w, h1[g][0], a0);
      a1 = fmaf(w, h1[g][1], a1);
    }
    h2[f][0] = fmaxf(a0, 0.f);
    h2[f][1] = fmaxf(a1, 0.f);
  }

  float* ob = out + (size_t)b * 15 * N + n0;
#pragma unroll
  for (int f = 0; f < 15; ++f) {
    const float* row = sP + 304 + f * 16;
    float bias = row[15];
    float a0 = bias, a1 = bias;
#pragma unroll
    for (int g = 0; g < 15; ++g) {
      float w = row[g];
      a0 = fmaf(w, h2[g][0], a0);
      a1 = fmaf(w, h2[g][1], a1);
    }
    *(float2*)(ob + (size_t)f * N) = make_float2(a0, a1);
  }
}

extern "C" void kernel_launch(void* const* d_in, const int* in_sizes, int n_in,
                              void* d_out, int out_size, void* d_ws, size_t ws_size,
                              hipStream_t stream) {
  const float* x  = (const float*)d_in[0];
  const float* R  = (const float*)d_in[1];
  const float* W1 = (const float*)d_in[2];
  const float* b1 = (const float*)d_in[3];
  const float* W2 = (const float*)d_in[4];
  const float* b2 = (const float*)d_in[5];
  const float* W3 = (const float*)d_in[6];
  const float* b3 = (const float*)d_in[7];
  const float* Q1 = (const float*)d_in[8];
  const float* Q2 = (const float*)d_in[9];
  const float* Q3 = (const float*)d_in[10];
  float* out = (float*)d_out;

  const int B = in_sizes[1] / 9;        // 32
  const int N = in_sizes[0] / (3 * B);  // 65536

  const int chunks = (N + 511) / 512;   // 256 threads * 2 pts
  fused_all<<<dim3(chunks, B), dim3(256), 0, stream>>>(
      x, R, W1, b1, W2, b2, W3, b3, Q1, Q2, Q3, out, N);
}

// Round 3
// 178.753 us; speedup vs baseline: 1.0250x; 1.0250x over previous
//
#include <hip/hip_runtime.h>

// ParamMakeFeature: out[b,:,n] = D_b * mlp(R_b^T x[b,:,n])
// Folded: A1 = W1*R^T, A3 = D*W3, c3 = D*b3,
//   D = blockdiag(Q1 R Q1^T, Q2 (RxR) Q2^T, Q3 (RxRxR) Q3^T).
// Kernel A (32 blocks, once): fold params into d_ws.
// Kernel B: pointwise 3->15->15->15 MLP; weights are BLOCK-UNIFORM loads
//   through a __restrict__ pointer -> compiler emits s_load into SGPRs
//   (scalar pipe), so the main loop has ZERO LDS traffic and v_fma takes
//   the weight as its SGPR operand. VALU (~14 us) hides under the
//   151 MB HBM stream (~23 us floor).

#define PSTRIDE 544  // [0..59] A1 15x{w0,w1,w2,b1} | [64..303] W2' 15x16 | [304..543] A3' 15x16

__global__ void prep_params(const float* __restrict__ R_,
                            const float* __restrict__ W1, const float* __restrict__ b1,
                            const float* __restrict__ W2, const float* __restrict__ b2,
                            const float* __restrict__ W3, const float* __restrict__ b3,
                            const float* __restrict__ Q1, const float* __restrict__ Q2,
                            const float* __restrict__ Q3,
                            float* __restrict__ P) {
  __shared__ float sR[9];
  __shared__ float sK2[81];
  __shared__ float sK3[729];
  __shared__ float sT2[45];
  __shared__ float sT3[189];
  __shared__ float sD1[9], sD2[25], sD3[49];

  const int b = blockIdx.x;
  const int t = threadIdx.x;
  const int bs = blockDim.x;
  const float* R = R_ + b * 9;

  if (t < 9) sR[t] = R[t];
  __syncthreads();

  for (int i = t; i < 81; i += bs) {
    int r = i / 9, c = i % 9;
    sK2[i] = sR[(r / 3) * 3 + (c / 3)] * sR[(r % 3) * 3 + (c % 3)];
  }
  for (int i = t; i < 729; i += bs) {
    int r = i / 27, c = i % 27;
    sK3[i] = sR[(r / 9) * 3 + (c / 9)] *
             sR[((r / 3) % 3) * 3 + ((c / 3) % 3)] *
             sR[(r % 3) * 3 + (c % 3)];
  }
  __syncthreads();

  for (int i = t; i < 45; i += bs) {
    int r = i / 5, q = i % 5;
    float acc = 0.f;
    for (int c = 0; c < 9; ++c) acc += sK2[r * 9 + c] * Q2[q * 9 + c];
    sT2[i] = acc;
  }
  for (int i = t; i < 189; i += bs) {
    int r = i / 7, q = i % 7;
    float acc = 0.f;
    for (int c = 0; c < 27; ++c) acc += sK3[r * 27 + c] * Q3[q * 27 + c];
    sT3[i] = acc;
  }
  __syncthreads();

  for (int i = t; i < 9; i += bs) {
    int p = i / 3, q = i % 3;
    float acc = 0.f;
    for (int ii = 0; ii < 3; ++ii)
      for (int jj = 0; jj < 3; ++jj)
        acc += Q1[p * 3 + ii] * sR[ii * 3 + jj] * Q1[q * 3 + jj];
    sD1[i] = acc;
  }
  for (int i = t; i < 25; i += bs) {
    int p = i / 5, q = i % 5;
    float acc = 0.f;
    for (int r2 = 0; r2 < 9; ++r2) acc += Q2[p * 9 + r2] * sT2[r2 * 5 + q];
    sD2[i] = acc;
  }
  for (int i = t; i < 49; i += bs) {
    int p = i / 7, q = i % 7;
    float acc = 0.f;
    for (int r2 = 0; r2 < 27; ++r2) acc += Q3[p * 27 + r2] * sT3[r2 * 7 + q];
    sD3[i] = acc;
  }
  __syncthreads();

  float* Pb = P + (size_t)b * PSTRIDE;

  for (int f = t; f < 15; f += bs) {
    for (int j = 0; j < 3; ++j) {
      float acc = 0.f;
      for (int i2 = 0; i2 < 3; ++i2) acc += W1[f * 3 + i2] * sR[j * 3 + i2];
      Pb[f * 4 + j] = acc;
    }
    Pb[f * 4 + 3] = b1[f];
  }
  for (int i = t; i < 240; i += bs) {
    int f = i / 16, k = i % 16;
    Pb[64 + i] = (k < 15) ? W2[f * 15 + k] : b2[f];
  }
  for (int i = t; i < 240; i += bs) {
    int f = i / 16, k = i % 16;
    float acc = 0.f;
    if (f < 3) {
      for (int q = 0; q < 3; ++q)
        acc += sD1[f * 3 + q] * ((k < 15) ? W3[q * 15 + k] : b3[q]);
    } else if (f < 8) {
      for (int q = 0; q < 5; ++q)
        acc += sD2[(f - 3) * 5 + q] * ((k < 15) ? W3[(q + 3) * 15 + k] : b3[q + 3]);
    } else {
      for (int q = 0; q < 7; ++q)
        acc += sD3[(f - 8) * 7 + q] * ((k < 15) ? W3[(q + 8) * 15 + k] : b3[q + 8]);
    }
    Pb[304 + i] = acc;
  }
}

// ---------------------------------------------------------------------------
// Main kernel: no LDS. All weight accesses are uniform (blockIdx-only
// addressing) -> scalar loads into SGPRs. 2 points/thread, float2 I/O.
// ---------------------------------------------------------------------------
__global__ __launch_bounds__(256, 4) void fused_mlp_rot(
    const float* __restrict__ x, const float* __restrict__ P,
    float* __restrict__ out, int N) {
  const int b = blockIdx.y;
  const int t = threadIdx.x;
  const float* __restrict__ Pb = P + (size_t)b * PSTRIDE;  // uniform base

  const int n0 = (blockIdx.x * 256 + t) * 2;
  if (n0 >= N) return;

  const float* xb = x + (size_t)b * 3 * N + n0;
  float2 xa = *(const float2*)(xb);
  float2 xm = *(const float2*)(xb + N);
  float2 xc = *(const float2*)(xb + 2 * N);

  // Layer 1: h1 = relu(A1 * x + b1)   (weights uniform -> SGPR)
  float h1[15][2];
#pragma unroll
  for (int f = 0; f < 15; ++f) {
    float w0 = Pb[f * 4 + 0], w1 = Pb[f * 4 + 1];
    float w2 = Pb[f * 4 + 2], w3 = Pb[f * 4 + 3];
    h1[f][0] = fmaxf(fmaf(w0, xa.x, fmaf(w1, xm.x, fmaf(w2, xc.x, w3))), 0.f);
    h1[f][1] = fmaxf(fmaf(w0, xa.y, fmaf(w1, xm.y, fmaf(w2, xc.y, w3))), 0.f);
  }

  // Layer 2: h2 = relu(W2 * h1 + b2)
  float h2[15][2];
#pragma unroll
  for (int f = 0; f < 15; ++f) {
    const float* __restrict__ row = Pb + 64 + f * 16;
    float bias = row[15];
    float a0 = bias, a1 = bias;
#pragma unroll
    for (int g = 0; g < 15; ++g) {
      float w = row[g];
      a0 = fmaf(w, h1[g][0], a0);
      a1 = fmaf(w, h1[g][1], a1);
    }
    h2[f][0] = fmaxf(a0, 0.f);
    h2[f][1] = fmaxf(a1, 0.f);
  }

  // Layer 3 (+rotation folded): out = A3 * h2 + c3
  float* ob = out + (size_t)b * 15 * N + n0;
#pragma unroll
  for (int f = 0; f < 15; ++f) {
    const float* __restrict__ row = Pb + 304 + f * 16;
    float bias = row[15];
    float a0 = bias, a1 = bias;
#pragma unroll
    for (int g = 0; g < 15; ++g) {
      float w = row[g];
      a0 = fmaf(w, h2[g][0], a0);
      a1 = fmaf(w, h2[g][1], a1);
    }
    *(float2*)(ob + (size_t)f * N) = make_float2(a0, a1);
  }
}

extern "C" void kernel_launch(void* const* d_in, const int* in_sizes, int n_in,
                              void* d_out, int out_size, void* d_ws, size_t ws_size,
                              hipStream_t stream) {
  const float* x  = (const float*)d_in[0];
  const float* R  = (const float*)d_in[1];
  const float* W1 = (const float*)d_in[2];
  const float* b1 = (const float*)d_in[3];
  const float* W2 = (const float*)d_in[4];
  const float* b2 = (const float*)d_in[5];
  const float* W3 = (const float*)d_in[6];
  const float* b3 = (const float*)d_in[7];
  const float* Q1 = (const float*)d_in[8];
  const float* Q2 = (const float*)d_in[9];
  const float* Q3 = (const float*)d_in[10];
  float* out = (float*)d_out;
  float* P   = (float*)d_ws;

  const int B = in_sizes[1] / 9;        // 32
  const int N = in_sizes[0] / (3 * B);  // 65536

  prep_params<<<dim3(B), dim3(128), 0, stream>>>(R, W1, b1, W2, b2, W3, b3,
                                                 Q1, Q2, Q3, P);

  const int chunks = (N + 511) / 512;   // 256 threads * 2 pts
  fused_mlp_rot<<<dim3(chunks, B), dim3(256), 0, stream>>>(x, P, out, N);
}